// Round 2
// baseline (613.369 us; speedup 1.0000x reference)
//
#include <hip/hip_runtime.h>
#include <cstdint>

// LoRA mixture kernel for B=8, S=4096, D=2048, R=4, N=32.
// Math: for batch b0, out = relu(0.25 * sum_{j=4b0}^{4b0+3} (x @ B_j) @ A_j).
// (The reference's count matrix c[b0][j] == 8 exactly for j in [4b0,4b0+4), /32 -> 0.25.)
//
// Pipeline (all on `stream`, ws only):
//   pack_b_kernel : Bpack[b0][d][16] contiguous per-d 64B lines (2 MB ws)
//   lora_h_kernel : H partials, row-per-lane (no cross-lane reduction), B via SGPRs
//   lora_out_kernel: out = relu(0.25 * H @ A_cat), A in VGPRs, coalesced float4 stores

namespace {

constexpr int D = 2048;
constexpr int R = 4;
constexpr int B = 8;
constexpr int S = 4096;
constexpr int NROWS = B * S;        // 32768 total rows
constexpr int SEGS = 2;             // d-reduction segments in kernel 1
constexpr int SEGD = D / SEGS;      // 1024
constexpr int T = 16;               // 4 adapters x rank 4

// ws layout (floats):
//   [0,               B*D*T)                 : Bpack   (2 MB)
//   [B*D*T,           B*D*T + SEGS*NROWS*T)  : Hpart   (4 MB)

__global__ __launch_bounds__(256) void pack_b_kernel(const float* __restrict__ ab,
                                                     float* __restrict__ bpack) {
  int idx = blockIdx.x * 256 + threadIdx.x;      // over B*D*T = 262144
  if (idx >= B * D * T) return;
  int t  = idx & 15;
  int d  = (idx >> 4) & (D - 1);
  int b0 = idx >> 15;
  int j = 4 * b0 + (t >> 2);                     // adapter id
  int r = t & 3;                                 // rank index
  bpack[idx] = ab[((size_t)j * D + d) * R + r];
}

// One wave per block; lane = row within a 64-row block; each lane reduces its
// own row over a 1024-wide d-segment. Bpack reads are wave-uniform -> SGPRs.
__global__ __launch_bounds__(64) void lora_h_kernel(const float* __restrict__ x,
                                                    const float* __restrict__ bpack,
                                                    float* __restrict__ hpart) {
  int w = blockIdx.x;                 // 0..1023
  int seg = w & (SEGS - 1);
  int rowblk = w >> 1;                // 0..511
  int row = rowblk * 64 + threadIdx.x;
  int b0 = row >> 12;                 // 4096 rows per batch
  const float* xr = x + (size_t)row * D + seg * SEGD;
  const float* bp = bpack + ((size_t)b0 * D + (size_t)seg * SEGD) * T;

  float acc[T];
#pragma unroll
  for (int t = 0; t < T; ++t) acc[t] = 0.f;

#pragma unroll 4
  for (int d4 = 0; d4 < SEGD; d4 += 4) {
    float4 xv = *reinterpret_cast<const float4*>(xr + d4);
    const float4* b4 = reinterpret_cast<const float4*>(bp + (size_t)d4 * T);
#pragma unroll
    for (int dd = 0; dd < 4; ++dd) {
      float xs = (&xv.x)[dd];
#pragma unroll
      for (int tq = 0; tq < 4; ++tq) {
        float4 bv = b4[dd * 4 + tq];             // uniform -> s_load
        acc[tq * 4 + 0] = fmaf(xs, bv.x, acc[tq * 4 + 0]);
        acc[tq * 4 + 1] = fmaf(xs, bv.y, acc[tq * 4 + 1]);
        acc[tq * 4 + 2] = fmaf(xs, bv.z, acc[tq * 4 + 2]);
        acc[tq * 4 + 3] = fmaf(xs, bv.w, acc[tq * 4 + 3]);
      }
    }
  }

  float4* hp = reinterpret_cast<float4*>(hpart + ((size_t)seg * NROWS + row) * T);
#pragma unroll
  for (int q = 0; q < 4; ++q)
    hp[q] = make_float4(acc[q * 4 + 0], acc[q * 4 + 1], acc[q * 4 + 2], acc[q * 4 + 3]);
}

// Each thread owns 4 contiguous output columns (float4); A_cat slice scaled by
// 0.25 lives in 64 VGPRs for a 64-row tile. H reads are wave-uniform -> s_load.
__global__ __launch_bounds__(256) void lora_out_kernel(const float* __restrict__ hpart,
                                                       const float* __restrict__ aa,
                                                       float* __restrict__ out) {
  int blk = blockIdx.x;               // 0..1023
  int chunk = blk & 1;                // d half
  int rt = blk >> 1;                  // 0..511 row tiles of 64
  int row0 = rt * 64;
  int b0 = row0 >> 12;
  int d = chunk * (D / 2) + threadIdx.x * 4;

  float4 a[T];
#pragma unroll
  for (int t = 0; t < T; ++t) {
    // A_cat row t for batch b0 is adapter_a row (16*b0 + t) of the [N*R][D] view.
    float4 v = *reinterpret_cast<const float4*>(aa + (size_t)(16 * b0 + t) * D + d);
    a[t] = make_float4(v.x * 0.25f, v.y * 0.25f, v.z * 0.25f, v.w * 0.25f);
  }

  for (int r0 = 0; r0 < 64; ++r0) {
    int row = row0 + r0;
    const float* h0 = hpart + (size_t)row * T;
    const float* h1 = hpart + ((size_t)NROWS + row) * T;
    float4 acc = make_float4(0.f, 0.f, 0.f, 0.f);
#pragma unroll
    for (int t = 0; t < T; ++t) {
      float h = h0[t] + h1[t];                   // uniform loads, VALU add
      acc.x = fmaf(h, a[t].x, acc.x);
      acc.y = fmaf(h, a[t].y, acc.y);
      acc.z = fmaf(h, a[t].z, acc.z);
      acc.w = fmaf(h, a[t].w, acc.w);
    }
    *reinterpret_cast<float4*>(out + (size_t)row * D + d) =
        make_float4(fmaxf(acc.x, 0.f), fmaxf(acc.y, 0.f),
                    fmaxf(acc.z, 0.f), fmaxf(acc.w, 0.f));
  }
}

}  // namespace

extern "C" void kernel_launch(void* const* d_in, const int* in_sizes, int n_in,
                              void* d_out, int out_size, void* d_ws, size_t ws_size,
                              hipStream_t stream) {
  const float* x  = (const float*)d_in[0];   // [8,4096,2048]
  const float* ab = (const float*)d_in[1];   // [32,2048,4]
  const float* aa = (const float*)d_in[2];   // [32,4,2048]
  float* out = (float*)d_out;                // [8,4096,2048]

  float* bpack = (float*)d_ws;                          // B*D*T floats  (2 MB)
  float* hpart = bpack + (size_t)B * D * T;             // SEGS*NROWS*T  (4 MB)

  pack_b_kernel<<<(B * D * T + 255) / 256, 256, 0, stream>>>(ab, bpack);
  lora_h_kernel<<<(NROWS / 64) * SEGS, 64, 0, stream>>>(x, bpack, hpart);
  lora_out_kernel<<<(NROWS / 64) * 2, 256, 0, stream>>>(hpart, aa, out);
}